// Round 2
// baseline (540.886 us; speedup 1.0000x reference)
//
#include <hip/hip_runtime.h>

#define N_NODES 100000
#define N_EDGES 1600000
#define D_FEAT  128
#define C_CLS   40
#define LN_EPS  1e-5f

#define RPB   256                         // rows per bucket
#define NBKT  ((N_NODES + RPB - 1) / RPB) // 391
#define BCAP  6144                        // padded slots/bucket (mean 4096, +32 sigma)
#define EPT   8                           // edges per thread in edge kernels
#define EBLK2 ((N_EDGES + 256*EPT - 1) / (256*EPT))  // 782
#define CONVB (N_NODES * 64 / 256)        // 25000 conversion blocks

typedef __attribute__((ext_vector_type(8))) short short8;
typedef __attribute__((ext_vector_type(4))) float floatx4;

// ---------- bf16 pack/unpack (storage only; accumulate fp32) ----------
__device__ inline unsigned pack_bf2(float x, float y) {
    unsigned xi = __float_as_uint(x);
    unsigned yi = __float_as_uint(y);
    unsigned lo = (xi + 0x7fffu + ((xi >> 16) & 1u)) >> 16;
    unsigned hi = (yi + 0x7fffu + ((yi >> 16) & 1u)) & 0xffff0000u;
    return lo | hi;
}
__device__ inline float bf_lo(unsigned v) { return __uint_as_float(v << 16); }
__device__ inline float bf_hi(unsigned v) { return __uint_as_float(v & 0xffff0000u); }
__device__ inline short bf16_of(float x) {
    unsigned u = __float_as_uint(x);
    return (short)((u + 0x7fffu + ((u >> 16) & 1u)) >> 16);
}

// ---- K1: fused feat->bf16 conversion + per-row degree count (global atomics,
// 1.6M atomics over 100K addresses => ~16/address, negligible contention) ----
__global__ __launch_bounds__(256) void convdeg_k(const float* __restrict__ feat,
                                                 unsigned* __restrict__ hb,
                                                 const int* __restrict__ row,
                                                 int* __restrict__ deg) {
    int t = threadIdx.x;
    if (blockIdx.x < EBLK2) {
        int e0 = blockIdx.x * (256 * EPT) + t;
        #pragma unroll
        for (int k = 0; k < EPT; k++) {
            int e = e0 + k * 256;
            if (e < N_EDGES) atomicAdd(&deg[row[e]], 1);
        }
        return;
    }
    int i = (blockIdx.x - EBLK2) * 256 + t;       // over N*64
    float2 v = ((const float2*)feat)[i];
    hb[i] = pack_bf2(v.x, v.y);
}

// ---- K2: per-bucket local scan of degrees -> rowinfo/cur/dinv/selfc.
// CSR region for bucket b is the fixed range [b*BCAP, ...): no global scan. ----
__global__ __launch_bounds__(256) void rowscan_k(const int* __restrict__ deg,
                                                 int2* __restrict__ rowinfo,
                                                 int* __restrict__ cur,
                                                 float* __restrict__ dinv,
                                                 float* __restrict__ selfc) {
    __shared__ int psc[RPB];
    int b = blockIdx.x, t = threadIdx.x;
    int r = b * RPB + t;
    int v = (r < N_NODES) ? deg[r] : 0;
    psc[t] = v;
    __syncthreads();
    for (int off = 1; off < 256; off <<= 1) {
        int x = (t >= off) ? psc[t - off] : 0;
        __syncthreads();
        psc[t] += x;
        __syncthreads();
    }
    if (r < N_NODES) {
        int start = b * BCAP + psc[t] - v;     // exclusive prefix, bucket-local
        float d = rsqrtf((float)v + 1.0f);
        rowinfo[r] = make_int2(start, start + v);
        cur[r]     = start;
        dinv[r]    = d;
        selfc[r]   = 0.5f + 0.5f * d * d;
    }
}

// ---- K3: single-pass scatter of edges into final CSR with final weight ----
__global__ __launch_bounds__(256) void scatter_k(const int* __restrict__ row,
                                                 const int* __restrict__ col,
                                                 int* __restrict__ cur,
                                                 const float* __restrict__ dinv,
                                                 int2* __restrict__ csr) {
    int t = threadIdx.x;
    int e0 = blockIdx.x * (256 * EPT) + t;
    #pragma unroll
    for (int k = 0; k < EPT; k++) {
        int e = e0 + k * 256;
        if (e < N_EDGES) {
            int r = row[e], c = col[e];
            int p = atomicAdd(&cur[r], 1);
            float w = (0.5f * dinv[r]) * dinv[c];
            csr[p] = make_int2(c, __float_as_int(w));
        }
    }
}

// ---------------- propagation: 16 lanes per node (4 nodes/wave), uint4 lane
// payload, 8-edge chunks with csr prefetch => ~4x memory-level parallelism.
__global__ __launch_bounds__(256) void prop_bf_k(const unsigned* __restrict__ hin,
                                                 unsigned* __restrict__ hout,
                                                 const int2* __restrict__ rowinfo,
                                                 const int2* __restrict__ csr,
                                                 const float* __restrict__ selfc) {
    int t = threadIdx.x;
    int wave = t >> 6, lane = t & 63;
    int q   = lane >> 4;               // quarter-wave id: which of 4 nodes
    int sub = lane & 15;               // 16 lanes x uint4 = 256 B per node
    int node = blockIdx.x * 16 + wave * 4 + q;   // N % 16 == 0
    const uint4* hin4 = (const uint4*)hin;

    uint4 hv = hin4[(unsigned)node * 16 + sub];
    float sc = selfc[node];
    float acc[8];
    acc[0] = bf_lo(hv.x) * sc; acc[1] = bf_hi(hv.x) * sc;
    acc[2] = bf_lo(hv.y) * sc; acc[3] = bf_hi(hv.y) * sc;
    acc[4] = bf_lo(hv.z) * sc; acc[5] = bf_hi(hv.z) * sc;
    acc[6] = bf_lo(hv.w) * sc; acc[7] = bf_hi(hv.w) * sc;

    int2 ri = rowinfo[node];
    int j = ri.x, end = ri.y;
    int base = ri.x;                   // always a valid csr index for this row region

    int2 e[8];
    #pragma unroll
    for (int k = 0; k < 8; k++) {
        int idx = (j + k < end) ? j + k : base;
        e[k] = csr[idx];
    }

    while (__any(j < end)) {
        // issue gathers for current chunk (predicated: dummies -> node 0, w=0)
        uint4 g[8];
        float w[8];
        #pragma unroll
        for (int k = 0; k < 8; k++) {
            bool val = (j + k < end);
            int  c   = val ? e[k].x : 0;
            w[k]     = val ? __int_as_float(e[k].y) : 0.0f;
            g[k] = hin4[(unsigned)c * 16 + sub];
        }
        int j2 = j + 8;
        // prefetch next chunk's csr under the outstanding gathers
        #pragma unroll
        for (int k = 0; k < 8; k++) {
            int idx = (j2 + k < end) ? j2 + k : base;
            e[k] = csr[idx];
        }
        #pragma unroll
        for (int k = 0; k < 8; k++) {
            acc[0] += w[k] * bf_lo(g[k].x); acc[1] += w[k] * bf_hi(g[k].x);
            acc[2] += w[k] * bf_lo(g[k].y); acc[3] += w[k] * bf_hi(g[k].y);
            acc[4] += w[k] * bf_lo(g[k].z); acc[5] += w[k] * bf_hi(g[k].z);
            acc[6] += w[k] * bf_lo(g[k].w); acc[7] += w[k] * bf_hi(g[k].w);
        }
        j = j2;
    }

    uint4 o;
    o.x = pack_bf2(acc[0], acc[1]);
    o.y = pack_bf2(acc[2], acc[3]);
    o.z = pack_bf2(acc[4], acc[5]);
    o.w = pack_bf2(acc[6], acc[7]);
    ((uint4*)hout)[(unsigned)node * 16 + sub] = o;
}

// ---- fused fc + LayerNorm via MFMA: one wave per 16-node tile ----
__global__ __launch_bounds__(256) void fcln_mfma_k(const unsigned* __restrict__ h,
                                                   const float* __restrict__ W,
                                                   const float* __restrict__ b,
                                                   const float* __restrict__ gamma,
                                                   const float* __restrict__ beta,
                                                   float* __restrict__ out) {
    int t = threadIdx.x;
    int wave = t >> 6, lane = t & 63;
    int m = lane & 15, quad = lane >> 4;
    int tile = blockIdx.x * 4 + wave;
    if (tile * 16 >= N_NODES) return;
    int node0 = tile * 16;

    short8 bfrag[3][4];
    float bias[3], gam[3], bet[3];
    #pragma unroll
    for (int ct = 0; ct < 3; ct++) {
        int c = ct * 16 + m;
        bool ok = (c < C_CLS);
        bias[ct] = ok ? b[c] : 0.0f;
        gam[ct]  = ok ? gamma[c] : 0.0f;
        bet[ct]  = ok ? beta[c] : 0.0f;
        #pragma unroll
        for (int ks = 0; ks < 4; ks++) {
            const float* wr = W + c * D_FEAT + ks * 32 + quad * 8;
            #pragma unroll
            for (int j = 0; j < 8; j++)
                bfrag[ct][ks][j] = ok ? bf16_of(wr[j]) : (short)0;
        }
    }

    floatx4 acc0 = {0.f,0.f,0.f,0.f}, acc1 = acc0, acc2 = acc0;
    #pragma unroll
    for (int ks = 0; ks < 4; ks++) {
        const uint4* ap = (const uint4*)&h[(node0 + m) * 64 + ks * 16 + quad * 4];
        uint4 araw = *ap;
        short8 afrag;
        afrag[0] = (short)(araw.x & 0xffff); afrag[1] = (short)(araw.x >> 16);
        afrag[2] = (short)(araw.y & 0xffff); afrag[3] = (short)(araw.y >> 16);
        afrag[4] = (short)(araw.z & 0xffff); afrag[5] = (short)(araw.z >> 16);
        afrag[6] = (short)(araw.w & 0xffff); afrag[7] = (short)(araw.w >> 16);
        acc0 = __builtin_amdgcn_mfma_f32_16x16x32_bf16(afrag, bfrag[0][ks], acc0, 0, 0, 0);
        acc1 = __builtin_amdgcn_mfma_f32_16x16x32_bf16(afrag, bfrag[1][ks], acc1, 0, 0, 0);
        acc2 = __builtin_amdgcn_mfma_f32_16x16x32_bf16(afrag, bfrag[2][ks], acc2, 0, 0, 0);
    }

    #pragma unroll
    for (int r = 0; r < 4; r++) { acc0[r] += bias[0]; acc1[r] += bias[1]; acc2[r] += bias[2]; }

    float s[4], ss[4];
    #pragma unroll
    for (int r = 0; r < 4; r++) {
        s[r]  = acc0[r] + acc1[r] + acc2[r];
        ss[r] = acc0[r]*acc0[r] + acc1[r]*acc1[r] + acc2[r]*acc2[r];
    }
    #pragma unroll
    for (int o = 1; o < 16; o <<= 1) {
        #pragma unroll
        for (int r = 0; r < 4; r++) {
            s[r]  += __shfl_xor(s[r], o);
            ss[r] += __shfl_xor(ss[r], o);
        }
    }

    #pragma unroll
    for (int r = 0; r < 4; r++) {
        int node = node0 + quad * 4 + r;
        float mean = s[r] * (1.0f / C_CLS);
        float var  = ss[r] * (1.0f / C_CLS) - mean * mean;
        float inv  = rsqrtf(var + LN_EPS);
        float* orow = out + (size_t)node * C_CLS;
        orow[m]      = (acc0[r] - mean) * inv * gam[0] + bet[0];
        orow[16 + m] = (acc1[r] - mean) * inv * gam[1] + bet[1];
        if (m < 8)
            orow[32 + m] = (acc2[r] - mean) * inv * gam[2] + bet[2];
    }
}

// ---------------- launch ----------------
extern "C" void kernel_launch(void* const* d_in, const int* in_sizes, int n_in,
                              void* d_out, int out_size, void* d_ws, size_t ws_size,
                              hipStream_t stream) {
    const float* feat  = (const float*)d_in[0];
    const int*   row   = (const int*)d_in[1];
    const int*   col   = (const int*)d_in[2];
    const float* W     = (const float*)d_in[3];
    const float* b     = (const float*)d_in[4];
    const float* gamma = (const float*)d_in[5];
    const float* beta  = (const float*)d_in[6];
    float* out = (float*)d_out;

    char* ws = (char*)d_ws;
    size_t off = 0;
    auto alloc = [&](size_t bytes) {
        size_t o = off;
        off = (off + bytes + 255) & ~(size_t)255;
        return o;
    };
    float*    dinv     = (float*)   (ws + alloc((size_t)N_NODES * 4));
    float*    selfc    = (float*)   (ws + alloc((size_t)N_NODES * 4));
    int2*     rowinfo  = (int2*)    (ws + alloc((size_t)N_NODES * 8));
    int*      deg      = (int*)     (ws + alloc((size_t)N_NODES * 4));
    int*      cur      = (int*)     (ws + alloc((size_t)N_NODES * 4));
    int2*     csr      = (int2*)    (ws + alloc((size_t)NBKT * BCAP * 8));
    unsigned* h0       = (unsigned*)(ws + alloc((size_t)N_NODES * 64 * 4));
    unsigned* h1       = (unsigned*)(ws + alloc((size_t)N_NODES * 64 * 4));

    hipMemsetAsync(deg, 0, (size_t)N_NODES * 4, stream);

    convdeg_k<<<EBLK2 + CONVB, 256, 0, stream>>>(feat, h0, row, deg);
    rowscan_k<<<NBKT, 256, 0, stream>>>(deg, rowinfo, cur, dinv, selfc);
    scatter_k<<<EBLK2, 256, 0, stream>>>(row, col, cur, dinv, csr);

    int pgrid = N_NODES / 16;
    prop_bf_k<<<pgrid, 256, 0, stream>>>(h0, h1, rowinfo, csr, selfc);
    prop_bf_k<<<pgrid, 256, 0, stream>>>(h1, h0, rowinfo, csr, selfc);
    prop_bf_k<<<pgrid, 256, 0, stream>>>(h0, h1, rowinfo, csr, selfc);
    prop_bf_k<<<pgrid, 256, 0, stream>>>(h1, h0, rowinfo, csr, selfc);

    int tiles = N_NODES / 16;                       // 6250
    int fblocks = (tiles + 3) / 4;                  // 1563
    fcln_mfma_k<<<fblocks, 256, 0, stream>>>(h0, W, b, gamma, beta, out);
}

// Round 3
// 431.465 us; speedup vs baseline: 1.2536x; 1.2536x over previous
//
#include <hip/hip_runtime.h>

#define N_NODES 100000
#define N_EDGES 1600000
#define D_FEAT  128
#define C_CLS   40
#define LN_EPS  1e-5f

#define RPB   256                         // rows per bucket
#define NBKT  ((N_NODES + RPB - 1) / RPB) // 391
#define BCAP  6144                        // padded slots/bucket (mean 4096, sigma~64)
#define TILE_E 4096                       // edges per bin block (round-0 proven)
#define EBLK  ((N_EDGES + TILE_E - 1) / TILE_E)  // 391
#define CONVB (N_NODES * 64 / 256)        // 25000 conv blocks

typedef __attribute__((ext_vector_type(8))) short short8;
typedef __attribute__((ext_vector_type(4))) float floatx4;

// ---------- bf16 pack/unpack (storage only; accumulate fp32) ----------
__device__ inline unsigned pack_bf2(float x, float y) {
    unsigned xi = __float_as_uint(x);
    unsigned yi = __float_as_uint(y);
    unsigned lo = (xi + 0x7fffu + ((xi >> 16) & 1u)) >> 16;
    unsigned hi = (yi + 0x7fffu + ((yi >> 16) & 1u)) & 0xffff0000u;
    return lo | hi;
}
__device__ inline float bf_lo(unsigned v) { return __uint_as_float(v << 16); }
__device__ inline float bf_hi(unsigned v) { return __uint_as_float(v & 0xffff0000u); }
__device__ inline short bf16_of(float x) {
    unsigned u = __float_as_uint(x);
    return (short)((u + 0x7fffu + ((u >> 16) & 1u)) >> 16);
}

// ---- fused: blocks [0,EBLK) bin edges into buckets; rest convert feat ----
// csr_tmp[b*BCAP + slot] = (lrow<<17) | col
__global__ __launch_bounds__(256) void convbin_k(const float* __restrict__ feat,
                                                 unsigned* __restrict__ hb,
                                                 const int* __restrict__ row,
                                                 const int* __restrict__ col,
                                                 int* __restrict__ bktsz,
                                                 int* __restrict__ csr_tmp) {
    int t = threadIdx.x;
    if (blockIdx.x >= EBLK) {
        int i = (blockIdx.x - EBLK) * 256 + t;       // over N*64
        float2 v = ((const float2*)feat)[i];
        hb[i] = pack_bf2(v.x, v.y);
        return;
    }
    __shared__ int hist[NBKT];
    __shared__ int cbase[NBKT];
    int tile = blockIdx.x * TILE_E;
    for (int i = t; i < NBKT; i += 256) hist[i] = 0;
    __syncthreads();
    int r[16], c[16], pos[16];
    #pragma unroll
    for (int k = 0; k < 16; k++) {
        int e = tile + k * 256 + t;
        if (e < N_EDGES) {
            r[k] = row[e]; c[k] = col[e];
            pos[k] = atomicAdd(&hist[r[k] / RPB], 1);
        } else r[k] = -1;
    }
    __syncthreads();
    for (int i = t; i < NBKT; i += 256) {
        int h = hist[i];
        cbase[i] = h ? atomicAdd(&bktsz[i], h) : 0;
    }
    __syncthreads();
    #pragma unroll
    for (int k = 0; k < 16; k++) {
        if (r[k] >= 0) {
            int b = r[k] / RPB;
            int slot = cbase[b] + pos[k];
            if (slot < BCAP)   // statistically impossible overflow guard
                csr_tmp[b * BCAP + slot] = ((r[k] & (RPB - 1)) << 17) | c[k];
        }
    }
}

// ---- refine A: per bucket, fine histogram + local scan -> rowinfo/dinv/selfc
// final CSR region for bucket b is [b*BCAP, b*BCAP+cnt): bucket-independent.
__global__ __launch_bounds__(256) void refineA_k(const int* __restrict__ csr_tmp,
                                                 const int* __restrict__ bktsz,
                                                 int2* __restrict__ rowinfo,
                                                 float* __restrict__ dinv,
                                                 float* __restrict__ selfc) {
    __shared__ int hist[RPB];
    __shared__ int psc[RPB];
    int b = blockIdx.x, t = threadIdx.x;
    int r0 = b * RPB;
    int nrows = min(RPB, N_NODES - r0);
    hist[t] = 0;
    __syncthreads();
    int cnt = bktsz[b];
    const int* base = csr_tmp + b * BCAP;
    for (int i = t; i < cnt; i += 256)
        atomicAdd(&hist[base[i] >> 17], 1);
    __syncthreads();
    int v = hist[t];
    psc[t] = v;
    __syncthreads();
    for (int off = 1; off < 256; off <<= 1) {
        int x = (t >= off) ? psc[t - off] : 0;
        __syncthreads();
        psc[t] += x;
        __syncthreads();
    }
    if (t < nrows) {
        int start = b * BCAP + psc[t] - v;     // exclusive prefix, bucket-local
        float d = rsqrtf((float)v + 1.0f);
        rowinfo[r0 + t] = make_int2(start, start + v);
        dinv[r0 + t]  = d;
        selfc[r0 + t] = 0.5f + 0.5f * d * d;
    }
}

// ---- refine B: scatter edges to final CSR with full weight ----
// bucket-ordered source + bucket-local destinations => write locality
__global__ __launch_bounds__(256) void refineB_k(const int* __restrict__ csr_tmp,
                                                 const int* __restrict__ bktsz,
                                                 const int2* __restrict__ rowinfo,
                                                 const float* __restrict__ dinv,
                                                 int2* __restrict__ csr) {
    __shared__ int   cur[RPB];
    __shared__ float dl[RPB];
    int b = blockIdx.x, t = threadIdx.x;
    int r0 = b * RPB;
    int nrows = min(RPB, N_NODES - r0);
    if (t < nrows) {
        cur[t] = rowinfo[r0 + t].x;
        dl[t]  = dinv[r0 + t];
    }
    __syncthreads();
    int cnt = bktsz[b];
    const int* base = csr_tmp + b * BCAP;
    for (int i = t; i < cnt; i += 256) {
        int pk = base[i];
        int lr = pk >> 17;
        int c  = pk & 0x1FFFF;
        int p = atomicAdd(&cur[lr], 1);
        float w = (0.5f * dl[lr]) * dinv[c];
        csr[p] = make_int2(c, __float_as_int(w));
    }
}

// ---------------- propagation: 16 lanes per node (4 nodes/wave), uint4 lane
// payload, 8-edge chunks with csr prefetch => ~4x memory-level parallelism.
__global__ __launch_bounds__(256) void prop_bf_k(const unsigned* __restrict__ hin,
                                                 unsigned* __restrict__ hout,
                                                 const int2* __restrict__ rowinfo,
                                                 const int2* __restrict__ csr,
                                                 const float* __restrict__ selfc) {
    int t = threadIdx.x;
    int wave = t >> 6, lane = t & 63;
    int q   = lane >> 4;               // quarter-wave id: which of 4 nodes
    int sub = lane & 15;               // 16 lanes x uint4 = 256 B per node
    int node = blockIdx.x * 16 + wave * 4 + q;   // N % 16 == 0
    const uint4* hin4 = (const uint4*)hin;

    uint4 hv = hin4[(unsigned)node * 16 + sub];
    float sc = selfc[node];
    float acc[8];
    acc[0] = bf_lo(hv.x) * sc; acc[1] = bf_hi(hv.x) * sc;
    acc[2] = bf_lo(hv.y) * sc; acc[3] = bf_hi(hv.y) * sc;
    acc[4] = bf_lo(hv.z) * sc; acc[5] = bf_hi(hv.z) * sc;
    acc[6] = bf_lo(hv.w) * sc; acc[7] = bf_hi(hv.w) * sc;

    int2 ri = rowinfo[node];
    int j = ri.x, end = ri.y;
    int base = ri.x;                   // always a valid csr index for this row region

    int2 e[8];
    #pragma unroll
    for (int k = 0; k < 8; k++) {
        int idx = (j + k < end) ? j + k : base;
        e[k] = csr[idx];
    }

    while (__any(j < end)) {
        // issue gathers for current chunk (predicated: dummies -> node 0, w=0)
        uint4 g[8];
        float w[8];
        #pragma unroll
        for (int k = 0; k < 8; k++) {
            bool val = (j + k < end);
            int  c   = val ? e[k].x : 0;
            w[k]     = val ? __int_as_float(e[k].y) : 0.0f;
            g[k] = hin4[(unsigned)c * 16 + sub];
        }
        int j2 = j + 8;
        // prefetch next chunk's csr under the outstanding gathers
        #pragma unroll
        for (int k = 0; k < 8; k++) {
            int idx = (j2 + k < end) ? j2 + k : base;
            e[k] = csr[idx];
        }
        #pragma unroll
        for (int k = 0; k < 8; k++) {
            acc[0] += w[k] * bf_lo(g[k].x); acc[1] += w[k] * bf_hi(g[k].x);
            acc[2] += w[k] * bf_lo(g[k].y); acc[3] += w[k] * bf_hi(g[k].y);
            acc[4] += w[k] * bf_lo(g[k].z); acc[5] += w[k] * bf_hi(g[k].z);
            acc[6] += w[k] * bf_lo(g[k].w); acc[7] += w[k] * bf_hi(g[k].w);
        }
        j = j2;
    }

    uint4 o;
    o.x = pack_bf2(acc[0], acc[1]);
    o.y = pack_bf2(acc[2], acc[3]);
    o.z = pack_bf2(acc[4], acc[5]);
    o.w = pack_bf2(acc[6], acc[7]);
    ((uint4*)hout)[(unsigned)node * 16 + sub] = o;
}

// ---- fused fc + LayerNorm via MFMA: one wave per 16-node tile ----
__global__ __launch_bounds__(256) void fcln_mfma_k(const unsigned* __restrict__ h,
                                                   const float* __restrict__ W,
                                                   const float* __restrict__ b,
                                                   const float* __restrict__ gamma,
                                                   const float* __restrict__ beta,
                                                   float* __restrict__ out) {
    int t = threadIdx.x;
    int wave = t >> 6, lane = t & 63;
    int m = lane & 15, quad = lane >> 4;
    int tile = blockIdx.x * 4 + wave;
    if (tile * 16 >= N_NODES) return;
    int node0 = tile * 16;

    short8 bfrag[3][4];
    float bias[3], gam[3], bet[3];
    #pragma unroll
    for (int ct = 0; ct < 3; ct++) {
        int c = ct * 16 + m;
        bool ok = (c < C_CLS);
        bias[ct] = ok ? b[c] : 0.0f;
        gam[ct]  = ok ? gamma[c] : 0.0f;
        bet[ct]  = ok ? beta[c] : 0.0f;
        #pragma unroll
        for (int ks = 0; ks < 4; ks++) {
            const float* wr = W + c * D_FEAT + ks * 32 + quad * 8;
            #pragma unroll
            for (int j = 0; j < 8; j++)
                bfrag[ct][ks][j] = ok ? bf16_of(wr[j]) : (short)0;
        }
    }

    floatx4 acc0 = {0.f,0.f,0.f,0.f}, acc1 = acc0, acc2 = acc0;
    #pragma unroll
    for (int ks = 0; ks < 4; ks++) {
        const uint4* ap = (const uint4*)&h[(node0 + m) * 64 + ks * 16 + quad * 4];
        uint4 araw = *ap;
        short8 afrag;
        afrag[0] = (short)(araw.x & 0xffff); afrag[1] = (short)(araw.x >> 16);
        afrag[2] = (short)(araw.y & 0xffff); afrag[3] = (short)(araw.y >> 16);
        afrag[4] = (short)(araw.z & 0xffff); afrag[5] = (short)(araw.z >> 16);
        afrag[6] = (short)(araw.w & 0xffff); afrag[7] = (short)(araw.w >> 16);
        acc0 = __builtin_amdgcn_mfma_f32_16x16x32_bf16(afrag, bfrag[0][ks], acc0, 0, 0, 0);
        acc1 = __builtin_amdgcn_mfma_f32_16x16x32_bf16(afrag, bfrag[1][ks], acc1, 0, 0, 0);
        acc2 = __builtin_amdgcn_mfma_f32_16x16x32_bf16(afrag, bfrag[2][ks], acc2, 0, 0, 0);
    }

    #pragma unroll
    for (int r = 0; r < 4; r++) { acc0[r] += bias[0]; acc1[r] += bias[1]; acc2[r] += bias[2]; }

    float s[4], ss[4];
    #pragma unroll
    for (int r = 0; r < 4; r++) {
        s[r]  = acc0[r] + acc1[r] + acc2[r];
        ss[r] = acc0[r]*acc0[r] + acc1[r]*acc1[r] + acc2[r]*acc2[r];
    }
    #pragma unroll
    for (int o = 1; o < 16; o <<= 1) {
        #pragma unroll
        for (int r = 0; r < 4; r++) {
            s[r]  += __shfl_xor(s[r], o);
            ss[r] += __shfl_xor(ss[r], o);
        }
    }

    #pragma unroll
    for (int r = 0; r < 4; r++) {
        int node = node0 + quad * 4 + r;
        float mean = s[r] * (1.0f / C_CLS);
        float var  = ss[r] * (1.0f / C_CLS) - mean * mean;
        float inv  = rsqrtf(var + LN_EPS);
        float* orow = out + (size_t)node * C_CLS;
        orow[m]      = (acc0[r] - mean) * inv * gam[0] + bet[0];
        orow[16 + m] = (acc1[r] - mean) * inv * gam[1] + bet[1];
        if (m < 8)
            orow[32 + m] = (acc2[r] - mean) * inv * gam[2] + bet[2];
    }
}

// ---------------- launch ----------------
extern "C" void kernel_launch(void* const* d_in, const int* in_sizes, int n_in,
                              void* d_out, int out_size, void* d_ws, size_t ws_size,
                              hipStream_t stream) {
    const float* feat  = (const float*)d_in[0];
    const int*   row   = (const int*)d_in[1];
    const int*   col   = (const int*)d_in[2];
    const float* W     = (const float*)d_in[3];
    const float* b     = (const float*)d_in[4];
    const float* gamma = (const float*)d_in[5];
    const float* beta  = (const float*)d_in[6];
    float* out = (float*)d_out;

    char* ws = (char*)d_ws;
    size_t off = 0;
    auto alloc = [&](size_t bytes) {
        size_t o = off;
        off = (off + bytes + 255) & ~(size_t)255;
        return o;
    };
    float*    dinv     = (float*)   (ws + alloc((size_t)N_NODES * 4));
    float*    selfc    = (float*)   (ws + alloc((size_t)N_NODES * 4));
    int2*     rowinfo  = (int2*)    (ws + alloc((size_t)N_NODES * 8));
    int*      bktsz    = (int*)     (ws + alloc((size_t)NBKT * 4));
    int*      csr_tmp  = (int*)     (ws + alloc((size_t)NBKT * BCAP * 4));
    int2*     csr      = (int2*)    (ws + alloc((size_t)NBKT * BCAP * 8));
    unsigned* h0       = (unsigned*)(ws + alloc((size_t)N_NODES * 64 * 4));
    unsigned* h1       = (unsigned*)(ws + alloc((size_t)N_NODES * 64 * 4));

    hipMemsetAsync(bktsz, 0, (size_t)NBKT * 4, stream);

    convbin_k<<<EBLK + CONVB, 256, 0, stream>>>(feat, h0, row, col, bktsz, csr_tmp);
    refineA_k<<<NBKT, 256, 0, stream>>>(csr_tmp, bktsz, rowinfo, dinv, selfc);
    refineB_k<<<NBKT, 256, 0, stream>>>(csr_tmp, bktsz, rowinfo, dinv, csr);

    int pgrid = N_NODES / 16;
    prop_bf_k<<<pgrid, 256, 0, stream>>>(h0, h1, rowinfo, csr, selfc);
    prop_bf_k<<<pgrid, 256, 0, stream>>>(h1, h0, rowinfo, csr, selfc);
    prop_bf_k<<<pgrid, 256, 0, stream>>>(h0, h1, rowinfo, csr, selfc);
    prop_bf_k<<<pgrid, 256, 0, stream>>>(h1, h0, rowinfo, csr, selfc);

    int tiles = N_NODES / 16;                       // 6250
    int fblocks = (tiles + 3) / 4;                  // 1563
    fcln_mfma_k<<<fblocks, 256, 0, stream>>>(h0, W, b, gamma, beta, out);
}